// Round 1
// baseline (496.530 us; speedup 1.0000x reference)
//
#include <hip/hip_runtime.h>
#include <hip/hip_bf16.h>
#include <math.h>

#define B_   16
#define N_   2304
#define C_   768
#define H_   12
#define D_   64
#define M_   (B_*N_)      // 36864
#define NQKV 2496
#define NPAD 2560
#define CC   832
#define EVS  (-1.0f/6912.0f)   // -SCALE/N = -(1/3)/2304

typedef __bf16 bf16x8 __attribute__((ext_vector_type(8)));
typedef __bf16 bf16x4 __attribute__((ext_vector_type(4)));
typedef float  f32x4  __attribute__((ext_vector_type(4)));

static __device__ __forceinline__ void gload_lds16(const void* g, void* l) {
  __builtin_amdgcn_global_load_lds((const __attribute__((address_space(1))) void*)g,
                                   (__attribute__((address_space(3))) void*)l, 16, 0, 0);
}

static __device__ __forceinline__ bf16x8 ld8(const __bf16* p) {
  // 8B-aligned LDS load as 2x bf16x4 (rows are stride-72 elements = 144B, not 16B aligned)
  bf16x4 lo = *(const bf16x4*)p;
  bf16x4 hi = *(const bf16x4*)(p + 4);
  return __builtin_shufflevector(lo, hi, 0,1,2,3,4,5,6,7);
}

// ---------------- converts ----------------
__global__ __launch_bounds__(256) void cvt_x(const float* __restrict__ in,
                                             __bf16* __restrict__ out, int n8) {
  int i = blockIdx.x * 256 + threadIdx.x;
  if (i >= n8) return;
  const float4* p = (const float4*)(in + (size_t)i * 8);
  float4 a = p[0], b = p[1];
  bf16x8 o = {(__bf16)a.x,(__bf16)a.y,(__bf16)a.z,(__bf16)a.w,
              (__bf16)b.x,(__bf16)b.y,(__bf16)b.z,(__bf16)b.w};
  *(bf16x8*)(out + (size_t)i * 8) = o;
}

__global__ __launch_bounds__(256) void cvt_wqkv(const float* __restrict__ w,
    const float* __restrict__ bias, __bf16* __restrict__ wout, float* __restrict__ bout) {
  int i = blockIdx.x * 256 + threadIdx.x;   // covers NPAD*96 = 245760
  if (i < NPAD * 96) {
    int n = i / 96, c8 = i - n * 96;
    bf16x8 o;
    if (n < NQKV) {
      const float4* p = (const float4*)(w + (size_t)n * 768 + c8 * 8);
      float4 a = p[0], b = p[1];
      o = (bf16x8){(__bf16)a.x,(__bf16)a.y,(__bf16)a.z,(__bf16)a.w,
                   (__bf16)b.x,(__bf16)b.y,(__bf16)b.z,(__bf16)b.w};
    } else {
      o = (bf16x8){(__bf16)0.f,(__bf16)0.f,(__bf16)0.f,(__bf16)0.f,
                   (__bf16)0.f,(__bf16)0.f,(__bf16)0.f,(__bf16)0.f};
    }
    *(bf16x8*)(wout + (size_t)n * 768 + c8 * 8) = o;
  }
  if (i < NPAD) bout[i] = (i < NQKV) ? bias[i] : 0.0f;
}

__global__ __launch_bounds__(256) void cvt_pw(const float* __restrict__ in,
                                              __bf16* __restrict__ out, int n8) {
  int i = blockIdx.x * 256 + threadIdx.x;
  if (i >= n8) return;
  const float4* p = (const float4*)(in + (size_t)i * 8);
  float4 a = p[0], b = p[1];
  bf16x8 o = {(__bf16)a.x,(__bf16)a.y,(__bf16)a.z,(__bf16)a.w,
              (__bf16)b.x,(__bf16)b.y,(__bf16)b.z,(__bf16)b.w};
  *(bf16x8*)(out + (size_t)i * 8) = o;
}

// ---------------- GEMM: C[m][n] = sum_k A[m][k]*Bt[n][k] + bias[n] ----------------
// 128x128 tile, BK=64, 256 threads (4 waves, 2x2), mfma_f32_16x16x32_bf16.
template<int OUTF32>
__global__ __launch_bounds__(256, 2) void gemm_bt(
    const __bf16* __restrict__ A, const __bf16* __restrict__ Bt,
    const float* __restrict__ bias, void* __restrict__ Cout,
    int M, int Nn, int K, int ldc)
{
  __shared__ __bf16 sA[128 * 64];
  __shared__ __bf16 sB[128 * 64];
  const int tid  = threadIdx.x;
  const int wid  = tid >> 6;
  const int lane = tid & 63;
  const int wr = wid >> 1, wc = wid & 1;
  const int l15 = lane & 15, lq = lane >> 4;
  const int bm = blockIdx.x, bn = blockIdx.y;

  f32x4 acc[4][4];
  #pragma unroll
  for (int i = 0; i < 4; ++i)
    #pragma unroll
    for (int j = 0; j < 4; ++j) acc[i][j] = (f32x4){0.f,0.f,0.f,0.f};

  const int sr  = tid >> 3;   // staging row 0..31 within 32-row group
  const int sc8 = tid & 7;    // 16B chunk within 128B row
  const __bf16* gA = A  + (size_t)((size_t)bm * 128 + sr) * K + sc8 * 8;
  const __bf16* gB = Bt + (size_t)((size_t)bn * 128 + sr) * K + sc8 * 8;

  const int ktn = K >> 6;
  for (int kt = 0; kt < ktn; ++kt) {
    const size_t ko = (size_t)kt * 64;
    #pragma unroll
    for (int i = 0; i < 4; ++i) {
      gload_lds16(gA + (size_t)(i * 32) * K + ko, sA + (i * 256 + wid * 64) * 8);
      gload_lds16(gB + (size_t)(i * 32) * K + ko, sB + (i * 256 + wid * 64) * 8);
    }
    __syncthreads();
    #pragma unroll
    for (int kk = 0; kk < 2; ++kk) {
      bf16x8 af[4], bfr[4];
      #pragma unroll
      for (int m = 0; m < 4; ++m) {
        int row = wr * 64 + m * 16 + l15;
        af[m] = *(const bf16x8*)&sA[row * 64 + kk * 32 + lq * 8];
      }
      #pragma unroll
      for (int n = 0; n < 4; ++n) {
        int col = wc * 64 + n * 16 + l15;
        bfr[n] = *(const bf16x8*)&sB[col * 64 + kk * 32 + lq * 8];
      }
      #pragma unroll
      for (int m = 0; m < 4; ++m)
        #pragma unroll
        for (int n = 0; n < 4; ++n)
          acc[m][n] = __builtin_amdgcn_mfma_f32_16x16x32_bf16(af[m], bfr[n], acc[m][n], 0, 0, 0);
    }
    __syncthreads();
  }

  #pragma unroll
  for (int n = 0; n < 4; ++n) {
    int col = bn * 128 + wc * 64 + n * 16 + l15;
    float bs = bias[col];
    #pragma unroll
    for (int m = 0; m < 4; ++m) {
      int row0 = bm * 128 + wr * 64 + m * 16 + lq * 4;
      #pragma unroll
      for (int r = 0; r < 4; ++r) {
        float v = acc[m][n][r] + bs;
        if (OUTF32) ((float*)Cout)[(size_t)(row0 + r) * ldc + col] = v;
        else        ((__bf16*)Cout)[(size_t)(row0 + r) * ldc + col] = (__bf16)v;
      }
    }
  }
}

// ---------------- inner swiglu: per (b,h) fast-weight update + apply ----------------
__global__ __launch_bounds__(256, 2) void inner_swiglu(
    const __bf16* __restrict__ qkv, const float* __restrict__ w1,
    const float* __restrict__ w2, __bf16* __restrict__ concat)
{
  const int bh = blockIdx.x;
  const int b = bh / H_, h = bh - b * H_;
  const int tid = threadIdx.x, wid = tid >> 6, lane = tid & 63;
  const int wr = wid >> 1, wc = wid & 1, l15 = lane & 15, lq = lane >> 4;

  __shared__ __bf16 w1T[64 * 72], w2T[64 * 72];
  __shared__ union U {
    struct { __bf16 kN[64 * 72], kT[64 * 72], t1T[64 * 72], t2T[64 * 72]; } c;
    struct { float g1[64 * 65], g2[64 * 65]; float nrm1[64], nrm2[64]; } g;
  } u;

  const float* w1p = w1 + h * 4096;
  const float* w2p = w2 + h * 4096;
  for (int idx = tid; idx < 4096; idx += 256) {
    int d = idx >> 6, e = idx & 63;
    w1T[e * 72 + d] = (__bf16)w1p[idx];
    w2T[e * 72 + d] = (__bf16)w2p[idx];
  }

  f32x4 g1a[2][2], g2a[2][2];
  #pragma unroll
  for (int i = 0; i < 2; ++i)
    #pragma unroll
    for (int j = 0; j < 2; ++j) { g1a[i][j] = (f32x4){0.f,0.f,0.f,0.f}; g2a[i][j] = (f32x4){0.f,0.f,0.f,0.f}; }

  const size_t rowb = (size_t)b * N_;
  const int koff = C_ + h * D_;        // k1 columns
  const int voff = 2 * C_ + h * D_;    // v1 columns
  __syncthreads();

  const int sn = tid >> 2, sdb = tid & 3;   // staging: row, 16-wide d block

  for (int ci = 0; ci < 36; ++ci) {
    const int n0 = ci * 64;
    { // stage k chunk: kN [n][d], kT [d][n]
      const __bf16* src = qkv + (rowb + n0 + sn) * (size_t)NPAD + koff + sdb * 16;
      bf16x8 va = *(const bf16x8*)src;
      bf16x8 vb = *(const bf16x8*)(src + 8);
      __bf16* kn = &u.c.kN[sn * 72 + sdb * 16];
      *(bf16x4*)(kn + 0)  = __builtin_shufflevector(va, va, 0,1,2,3);
      *(bf16x4*)(kn + 4)  = __builtin_shufflevector(va, va, 4,5,6,7);
      *(bf16x4*)(kn + 8)  = __builtin_shufflevector(vb, vb, 0,1,2,3);
      *(bf16x4*)(kn + 12) = __builtin_shufflevector(vb, vb, 4,5,6,7);
      #pragma unroll
      for (int j = 0; j < 8; ++j) u.c.kT[(sdb * 16 + j) * 72 + sn] = va[j];
      #pragma unroll
      for (int j = 0; j < 8; ++j) u.c.kT[(sdb * 16 + 8 + j) * 72 + sn] = vb[j];
    }
    __syncthreads();

    // z1 = k@w1, z2 = k@w2  (each wave: 32x32 tile)
    f32x4 z1[2][2], z2[2][2];
    #pragma unroll
    for (int i = 0; i < 2; ++i)
      #pragma unroll
      for (int j = 0; j < 2; ++j) { z1[i][j] = (f32x4){0.f,0.f,0.f,0.f}; z2[i][j] = (f32x4){0.f,0.f,0.f,0.f}; }
    #pragma unroll
    for (int kk = 0; kk < 2; ++kk) {
      bf16x8 af[2], b1[2], b2[2];
      #pragma unroll
      for (int mi = 0; mi < 2; ++mi)
        af[mi] = ld8(&u.c.kN[(wr * 32 + mi * 16 + l15) * 72 + kk * 32 + lq * 8]);
      #pragma unroll
      for (int ni = 0; ni < 2; ++ni) {
        int e = wc * 32 + ni * 16 + l15;
        b1[ni] = ld8(&w1T[e * 72 + kk * 32 + lq * 8]);
        b2[ni] = ld8(&w2T[e * 72 + kk * 32 + lq * 8]);
      }
      #pragma unroll
      for (int mi = 0; mi < 2; ++mi)
        #pragma unroll
        for (int ni = 0; ni < 2; ++ni) {
          z1[mi][ni] = __builtin_amdgcn_mfma_f32_16x16x32_bf16(af[mi], b1[ni], z1[mi][ni], 0, 0, 0);
          z2[mi][ni] = __builtin_amdgcn_mfma_f32_16x16x32_bf16(af[mi], b2[ni], z2[mi][ni], 0, 0, 0);
        }
    }

    // elementwise -> t1T [e][n], t2T [e][n]
    #pragma unroll
    for (int mi = 0; mi < 2; ++mi)
      #pragma unroll
      for (int ni = 0; ni < 2; ++ni) {
        int nl = wr * 32 + mi * 16 + lq * 4;
        int e  = wc * 32 + ni * 16 + l15;
        const __bf16* vp = qkv + (rowb + n0 + nl) * (size_t)NPAD + voff + e;
        #pragma unroll
        for (int r = 0; r < 4; ++r) {
          float vv  = (float)vp[(size_t)r * NPAD];
          float ev  = vv * EVS;
          float z1v = z1[mi][ni][r], z2v = z2[mi][ni][r];
          float sg  = 1.0f / (1.0f + __expf(-z2v));
          float t1  = ev * (z2v * sg);
          float t2  = ev * z1v * (sg * (1.0f + z2v * (1.0f - sg)));
          u.c.t1T[e * 72 + nl + r] = (__bf16)t1;
          u.c.t2T[e * 72 + nl + r] = (__bf16)t2;
        }
      }
    __syncthreads();

    // g += k^T @ t  (each wave: 32x32 tile of [d][e])
    #pragma unroll
    for (int kk = 0; kk < 2; ++kk) {
      bf16x8 af[2], b1[2], b2[2];
      #pragma unroll
      for (int mi = 0; mi < 2; ++mi)
        af[mi] = ld8(&u.c.kT[(wr * 32 + mi * 16 + l15) * 72 + kk * 32 + lq * 8]);
      #pragma unroll
      for (int ni = 0; ni < 2; ++ni) {
        int e = wc * 32 + ni * 16 + l15;
        b1[ni] = ld8(&u.c.t1T[e * 72 + kk * 32 + lq * 8]);
        b2[ni] = ld8(&u.c.t2T[e * 72 + kk * 32 + lq * 8]);
      }
      #pragma unroll
      for (int mi = 0; mi < 2; ++mi)
        #pragma unroll
        for (int ni = 0; ni < 2; ++ni) {
          g1a[mi][ni] = __builtin_amdgcn_mfma_f32_16x16x32_bf16(af[mi], b1[ni], g1a[mi][ni], 0, 0, 0);
          g2a[mi][ni] = __builtin_amdgcn_mfma_f32_16x16x32_bf16(af[mi], b2[ni], g2a[mi][ni], 0, 0, 0);
        }
    }
    __syncthreads();
  }

  // stage g to LDS (f32), col-norm over d, update weights into w1T/w2T (transposed bf16)
  #pragma unroll
  for (int mi = 0; mi < 2; ++mi)
    #pragma unroll
    for (int ni = 0; ni < 2; ++ni)
      #pragma unroll
      for (int r = 0; r < 4; ++r) {
        int d = wr * 32 + mi * 16 + lq * 4 + r;
        int e = wc * 32 + ni * 16 + l15;
        u.g.g1[d * 65 + e] = g1a[mi][ni][r];
        u.g.g2[d * 65 + e] = g2a[mi][ni][r];
      }
  __syncthreads();
  if (tid < 128) {
    const float* gs = (tid < 64) ? u.g.g1 : u.g.g2;
    int e = tid & 63;
    float s = 0.f;
    for (int d = 0; d < 64; ++d) { float gv = gs[d * 65 + e]; s += gv * gv; }
    float rn = 1.0f / (sqrtf(s) + 1.0f);
    if (tid < 64) u.g.nrm1[e] = rn; else u.g.nrm2[e] = rn;
  }
  __syncthreads();
  for (int idx = tid; idx < 4096; idx += 256) {
    int d = idx >> 6, e = idx & 63;
    float wu1 = w1p[idx] - u.g.g1[d * 65 + e] * u.g.nrm1[e];
    float wu2 = w2p[idx] - u.g.g2[d * 65 + e] * u.g.nrm2[e];
    w1T[e * 72 + d] = (__bf16)wu1;
    w2T[e * 72 + d] = (__bf16)wu2;
  }
  __syncthreads();

  // phase 2: x1 = (q@w1u) * silu(q@w2u) -> concat[:, h*64+e]
  const int qoff = h * D_;
  for (int ci = 0; ci < 36; ++ci) {
    const int n0 = ci * 64;
    {
      const __bf16* src = qkv + (rowb + n0 + sn) * (size_t)NPAD + qoff + sdb * 16;
      bf16x8 va = *(const bf16x8*)src;
      bf16x8 vb = *(const bf16x8*)(src + 8);
      __bf16* kn = &u.c.kN[sn * 72 + sdb * 16];
      *(bf16x4*)(kn + 0)  = __builtin_shufflevector(va, va, 0,1,2,3);
      *(bf16x4*)(kn + 4)  = __builtin_shufflevector(va, va, 4,5,6,7);
      *(bf16x4*)(kn + 8)  = __builtin_shufflevector(vb, vb, 0,1,2,3);
      *(bf16x4*)(kn + 12) = __builtin_shufflevector(vb, vb, 4,5,6,7);
    }
    __syncthreads();
    f32x4 y1[2][2], y2[2][2];
    #pragma unroll
    for (int i = 0; i < 2; ++i)
      #pragma unroll
      for (int j = 0; j < 2; ++j) { y1[i][j] = (f32x4){0.f,0.f,0.f,0.f}; y2[i][j] = (f32x4){0.f,0.f,0.f,0.f}; }
    #pragma unroll
    for (int kk = 0; kk < 2; ++kk) {
      bf16x8 af[2], b1[2], b2[2];
      #pragma unroll
      for (int mi = 0; mi < 2; ++mi)
        af[mi] = ld8(&u.c.kN[(wr * 32 + mi * 16 + l15) * 72 + kk * 32 + lq * 8]);
      #pragma unroll
      for (int ni = 0; ni < 2; ++ni) {
        int e = wc * 32 + ni * 16 + l15;
        b1[ni] = ld8(&w1T[e * 72 + kk * 32 + lq * 8]);
        b2[ni] = ld8(&w2T[e * 72 + kk * 32 + lq * 8]);
      }
      #pragma unroll
      for (int mi = 0; mi < 2; ++mi)
        #pragma unroll
        for (int ni = 0; ni < 2; ++ni) {
          y1[mi][ni] = __builtin_amdgcn_mfma_f32_16x16x32_bf16(af[mi], b1[ni], y1[mi][ni], 0, 0, 0);
          y2[mi][ni] = __builtin_amdgcn_mfma_f32_16x16x32_bf16(af[mi], b2[ni], y2[mi][ni], 0, 0, 0);
        }
    }
    #pragma unroll
    for (int mi = 0; mi < 2; ++mi)
      #pragma unroll
      for (int ni = 0; ni < 2; ++ni) {
        int nl = wr * 32 + mi * 16 + lq * 4;
        int e  = wc * 32 + ni * 16 + l15;
        #pragma unroll
        for (int r = 0; r < 4; ++r) {
          float a1 = y1[mi][ni][r], a2 = y2[mi][ni][r];
          float sg = 1.0f / (1.0f + __expf(-a2));
          concat[(rowb + n0 + nl + r) * (size_t)CC + h * D_ + e] = (__bf16)(a1 * (a2 * sg));
        }
      }
    __syncthreads();
  }
}

// ---------------- dwc path ----------------
__global__ __launch_bounds__(256) void dwc_grad(const __bf16* __restrict__ qkv,
    const float* __restrict__ w3, float* __restrict__ w3u) {
  int bd = blockIdx.x, b = bd >> 6, dd = bd & 63;
  int tid = threadIdx.x;
  __shared__ float kpad[50 * 50];
  __shared__ float red[9][4];
  for (int i = tid; i < 2500; i += 256) kpad[i] = 0.f;
  __syncthreads();
  const size_t base = (size_t)b * N_ * NPAD;
  for (int p = tid; p < 2304; p += 256) {
    int y = p / 48, x = p - y * 48;
    kpad[(y + 1) * 50 + x + 1] = (float)qkv[base + (size_t)p * NPAD + 2368 + dd];
  }
  __syncthreads();
  float acc[9];
  #pragma unroll
  for (int j = 0; j < 9; ++j) acc[j] = 0.f;
  for (int p = tid; p < 2304; p += 256) {
    int y = p / 48, x = p - y * 48;
    float e = (float)qkv[base + (size_t)p * NPAD + 2432 + dd] * EVS;
    #pragma unroll
    for (int j = 0; j < 9; ++j) {
      int ys = j / 3, xs = j - ys * 3;
      acc[j] += kpad[(y + ys) * 50 + (x + xs)] * e;
    }
  }
  #pragma unroll
  for (int j = 0; j < 9; ++j)
    for (int off = 32; off; off >>= 1) acc[j] += __shfl_down(acc[j], off);
  if ((tid & 63) == 0) {
    #pragma unroll
    for (int j = 0; j < 9; ++j) red[j][tid >> 6] = acc[j];
  }
  __syncthreads();
  if (tid == 0) {
    float g[9]; float ss = 0.f;
    #pragma unroll
    for (int j = 0; j < 9; ++j) {
      g[j] = red[j][0] + red[j][1] + red[j][2] + red[j][3];
      ss += g[j] * g[j];
    }
    float rn = 1.0f / (sqrtf(ss) + 1.0f);
    #pragma unroll
    for (int j = 0; j < 9; ++j) w3u[bd * 9 + j] = w3[dd * 9 + j] - g[j] * rn;
  }
}

__global__ __launch_bounds__(256) void dwc_apply(const __bf16* __restrict__ qkv,
    const float* __restrict__ w3u, __bf16* __restrict__ concat) {
  int bd = blockIdx.x, b = bd >> 6, dd = bd & 63;
  int tid = threadIdx.x;
  __shared__ float qpad[50 * 50];
  for (int i = tid; i < 2500; i += 256) qpad[i] = 0.f;
  __syncthreads();
  const size_t base = (size_t)b * N_ * NPAD;
  for (int p = tid; p < 2304; p += 256) {
    int y = p / 48, x = p - y * 48;
    qpad[(y + 1) * 50 + x + 1] = (float)qkv[base + (size_t)p * NPAD + 2304 + dd];
  }
  __syncthreads();
  float wv[9];
  #pragma unroll
  for (int j = 0; j < 9; ++j) wv[j] = w3u[bd * 9 + j];
  for (int p = tid; p < 2304; p += 256) {
    int y = p / 48, x = p - y * 48;
    float s = 0.f;
    #pragma unroll
    for (int j = 0; j < 9; ++j) {
      int ys = j / 3, xs = j - ys * 3;
      s += qpad[(y + ys) * 50 + (x + xs)] * wv[j];
    }
    concat[((size_t)b * N_ + p) * CC + 768 + dd] = (__bf16)s;
  }
}

// ---------------- launcher ----------------
extern "C" void kernel_launch(void* const* d_in, const int* in_sizes, int n_in,
                              void* d_out, int out_size, void* d_ws, size_t ws_size,
                              hipStream_t stream) {
  const float* x      = (const float*)d_in[0];
  const float* qkv_w  = (const float*)d_in[1];
  const float* qkv_b  = (const float*)d_in[2];
  const float* w1     = (const float*)d_in[3];
  const float* w2     = (const float*)d_in[4];
  const float* w3     = (const float*)d_in[5];
  const float* proj_w = (const float*)d_in[6];
  const float* proj_b = (const float*)d_in[7];

  char* ws = (char*)d_ws;
  // region A (lifetime 1): x_bf16 [36864][768], wqkv [2560][768], bias [2560]
  // region A (lifetime 2): concat [36864][832] bf16  (reuse, starts at 0)
  __bf16* xb     = (__bf16*)ws;                     // 56,623,104 B
  __bf16* wqkvb  = (__bf16*)(ws + 56623104);        //  3,932,160 B
  float*  qkvbp  = (float*) (ws + 60555264);        //     10,240 B
  __bf16* concat = (__bf16*)ws;                     // 61,341,696 B (reuse)
  __bf16* qkvb16 = (__bf16*)(ws + 61341696);        // 188,743,680 B
  __bf16* pwb    = (__bf16*)(ws + 250085376);       //  1,277,952 B
  float*  w3u    = (float*) (ws + 251363328);       //     36,864 B

  cvt_x   <<<13824, 256, 0, stream>>>(x, xb, 3538944);
  cvt_wqkv<<<  960, 256, 0, stream>>>(qkv_w, qkv_b, wqkvb, qkvbp);
  cvt_pw  <<<  312, 256, 0, stream>>>(proj_w, pwb, 79872);

  gemm_bt<0><<<dim3(288, 20), 256, 0, stream>>>(xb, wqkvb, qkvbp, (void*)qkvb16,
                                                M_, NPAD, 768, NPAD);

  inner_swiglu<<<192, 256, 0, stream>>>(qkvb16, w1, w2, concat);
  dwc_grad <<<1024, 256, 0, stream>>>(qkvb16, w3, w3u);
  dwc_apply<<<1024, 256, 0, stream>>>(qkvb16, w3u, concat);

  gemm_bt<1><<<dim3(288, 6), 256, 0, stream>>>(concat, pwb, proj_b, d_out,
                                               M_, 768, CC, 768);
}